// Round 2
// baseline (63.031 us; speedup 1.0000x reference)
//
#include <hip/hip_runtime.h>
#include <math.h>

#define BTOT 262144
#define R 3
#define F 4
#define H 16
#define A 18
#define SMALL_NUM_F 0.015f
#define MARGIN_TAU 3e-4f

// ---------------------------------------------------------------------------
// Setup kernel: runs once per launch (1 block). Computes into ws:
//   wsi[0]          : flag = (all b1 == 0 && all b2 == 0) ? 1 : 0
//   wsf[4 .. 15]    : K+[rf]  (collapsed MLP slope for s_f > 0), f64-accum
//   wsf[20 .. 31]   : K-[rf]  (collapsed MLP slope for s_f < 0)
// Derivation (b1=b2=0):  h1[h] = lrelu(sf*W1[h]) = sf * c_h,
//   c+_h = W1[h]*(W1[h]>0?1:0.01), c-_h = W1[h]*(W1[h]<0?1:0.01)
//   acc[o] = sf*P[o], P[o] = sum_h c_h W2[h][o]
//   h2[o] = lrelu(acc[o]) = sf*d_o, d+_o = P+[o]*(P+[o]>0?1:0.01),
//                                   d-_o = P-[o]*(P-[o]<0?1:0.01)
//   dot = sf*K + b3,  K = sum_o d_o W3[o]
// ---------------------------------------------------------------------------
__global__ __launch_bounds__(192) void ftc_setup(
    const float* __restrict__ W1,
    const float* __restrict__ b1,
    const float* __restrict__ W2,
    const float* __restrict__ b2,
    const float* __restrict__ W3,
    float* __restrict__ ws)
{
    __shared__ int nz;
    const int tid = threadIdx.x;
    if (tid == 0) nz = 0;
    __syncthreads();
    if (tid < R * F * H) {
        if (b1[tid] != 0.0f) atomicOr(&nz, 1);
        if (b2[tid] != 0.0f) atomicOr(&nz, 1);
    }
    __syncthreads();
    if (tid == 0) ((int*)ws)[0] = (nz == 0) ? 1 : 0;

    if (tid < R * F) {
        const int rf = tid;
        double Kp = 0.0, Km = 0.0;
        for (int o = 0; o < H; ++o) {
            double Pp = 0.0, Pm = 0.0;
            for (int h = 0; h < H; ++h) {
                const double w1 = (double)W1[rf * H + h];
                const double w2 = (double)W2[rf * H * H + h * H + o];
                Pp += w1 * ((w1 > 0.0) ? 1.0 : 0.01) * w2;
                Pm += w1 * ((w1 < 0.0) ? 1.0 : 0.01) * w2;
            }
            const double w3 = (double)W3[rf * H + o];
            Kp += Pp * ((Pp > 0.0) ? 1.0 : 0.01) * w3;
            Km += Pm * ((Pm < 0.0) ? 1.0 : 0.01) * w3;
        }
        ws[4 + rf]  = (float)Kp;
        ws[20 + rf] = (float)Km;
    }
}

// ---------------------------------------------------------------------------
// Exact full-precision MLP (identical math to the verified round-1 kernel).
// ---------------------------------------------------------------------------
__device__ __forceinline__ void compute_m_exact(
    const float sf[F],
    const float* __restrict__ W1, const float* __restrict__ b1,
    const float* __restrict__ W2, const float* __restrict__ b2,
    const float* __restrict__ W3, const float* __restrict__ b3,
    float m[R][F])
{
#pragma unroll
    for (int r = 0; r < R; ++r) {
#pragma unroll
        for (int f = 0; f < F; ++f) {
            const int rf = r * F + f;
            const float* w1  = W1 + rf * H;
            const float* bb1 = b1 + rf * H;
            const float* w2  = W2 + rf * H * H;
            const float* bb2 = b2 + rf * H;
            const float* w3  = W3 + rf * H;

            float h1[H];
#pragma unroll
            for (int h = 0; h < H; ++h) {
                float v = fmaf(sf[f], w1[h], bb1[h]);
                h1[h] = fmaxf(v, 0.01f * v);
            }
            float acc[H];
#pragma unroll
            for (int o = 0; o < H; ++o) acc[o] = bb2[o];
#pragma unroll
            for (int h = 0; h < H; ++h) {
                const float hv = h1[h];
#pragma unroll
                for (int o = 0; o < H; ++o)
                    acc[o] = fmaf(hv, w2[h * H + o], acc[o]);
            }
            float dot = b3[rf];
#pragma unroll
            for (int o = 0; o < H; ++o) {
                float v = fmaxf(acc[o], 0.01f * acc[o]);
                dot = fmaf(v, w3[o], dot);
            }
            float mm = 1.0f / (1.0f + expf(-dot));
            m[r][f] = fmaxf(mm, SMALL_NUM_F);
        }
    }
}

__device__ __forceinline__ void compute_strength(
    const float m[R][F],
    const float shg[R][F],
    const float shcond[R],
    float st[R])
{
#pragma unroll
    for (int r = 0; r < R; ++r) {
        const bool c = shcond[r] != 0.0f;
        float X[F];
        float ssum = 0.f;
#pragma unroll
        for (int f = 0; f < F; ++f) {
            float g = shg[r][f];
            float xw = expf(0.1f * (g / m[r][f]));
            if (c) xw *= g;
            X[f] = xw;
            ssum += xw;
        }
        float sv = 0.f;
#pragma unroll
        for (int f = 0; f < F; ++f)
            sv += m[r][f] * (X[f] / ssum) * shg[r][f];
        st[r] = isnan(sv) ? 0.0f : sv;
    }
}

__global__ __launch_bounds__(256) void ftc_kernel(
    const float* __restrict__ s,
    const float* __restrict__ W1,
    const float* __restrict__ b1,
    const float* __restrict__ W2,
    const float* __restrict__ b2,
    const float* __restrict__ W3,
    const float* __restrict__ b3,
    const float* __restrict__ p_select,
    const float* __restrict__ leaves,
    const float* __restrict__ gumbel,
    const float* __restrict__ ws,
    float* __restrict__ out)
{
    __shared__ float sh_g[R][F];
    __shared__ float sh_cond[R];
    __shared__ float sh_leaves[4][A];
    __shared__ unsigned char sh_idx[256];

    const int tid = threadIdx.x;

    if (tid < R * F) {
        const int rf = tid;
        float l0 = p_select[rf * 2 + 0] + gumbel[rf * 2 + 0];
        float l1 = p_select[rf * 2 + 1] + gumbel[rf * 2 + 1];
        float mx = fmaxf(l0, l1);
        float e0 = expf(l0 - mx), e1 = expf(l1 - mx);
        float den = e0 + e1;
        float y0 = e0 / den, y1 = e1 / den;
        float ym = fmaxf(y0, y1);
        sh_g[rf / F][rf % F] = (y1 == ym) ? 1.0f : 0.0f;
    }
    if (tid < 4) {
        float mx = leaves[tid * A];
        for (int a = 1; a < A; ++a) mx = fmaxf(mx, leaves[tid * A + a]);
        float e[A];
        float sum = 0.f;
        for (int a = 0; a < A; ++a) { e[a] = expf(leaves[tid * A + a] - mx); sum += e[a]; }
        for (int a = 0; a < A; ++a) sh_leaves[tid][a] = e[a] / sum;
    }
    __syncthreads();
    if (tid < R) {
        float ssum = sh_g[tid][0] + sh_g[tid][1] + sh_g[tid][2] + sh_g[tid][3];
        sh_cond[tid] = (ssum > SMALL_NUM_F) ? 1.0f : 0.0f;
    }
    __syncthreads();

    const int b = blockIdx.x * 256 + tid;
    const float4 sv = *reinterpret_cast<const float4*>(s + (size_t)b * F);
    const float sf[F] = {sv.x, sv.y, sv.z, sv.w};

    const int flag = ((const int*)ws)[0];

    float m[R][F];
    float st[R];
    bool need_exact = (flag == 0);

    if (flag) {
        // ---- collapsed fast path: m = sigmoid(sf*K(sign) + b3) ----
#pragma unroll
        for (int r = 0; r < R; ++r) {
#pragma unroll
            for (int f = 0; f < F; ++f) {
                const int rf = r * F + f;
                const float kp = ws[4 + rf];
                const float km = ws[20 + rf];
                const float k = (sf[f] > 0.0f) ? kp : km;
                const float dot = fmaf(sf[f], k, b3[rf]);
                const float mm = 1.0f / (1.0f + expf(-dot));
                m[r][f] = fmaxf(mm, SMALL_NUM_F);
            }
        }
        compute_strength(m, sh_g, sh_cond, st);
        // top-2 margin of the 4 path probabilities; if too close, the
        // ~1e-6-level deviation of the collapsed m could flip argmax ->
        // recompute exactly for those lanes.
        {
            const float r0 = st[0], r1 = st[1], r2 = st[2];
            const float p0 = r0 * r1;
            const float p1 = r0 * (1.0f - r1);
            const float p2 = (1.0f - r0) * r2;
            const float p3 = (1.0f - r0) * (1.0f - r2);
            const float a = fmaxf(p0, p1), bb = fminf(p0, p1);
            const float c = fmaxf(p2, p3), d = fminf(p2, p3);
            const float best = fmaxf(a, c);
            const float second = fmaxf(fminf(a, c), (a >= c) ? bb : d);
            const float margin = best - second;
            need_exact = !(margin > MARGIN_TAU);
        }
    }

    if (need_exact) {
        compute_m_exact(sf, W1, b1, W2, b2, W3, b3, m);
    }

    compute_strength(m, sh_g, sh_cond, st);

    const float r0 = st[0], r1 = st[1], r2 = st[2];
    const float p0 = r0 * r1;
    const float p1 = r0 * (1.0f - r1);
    const float p2 = (1.0f - r0) * r2;
    const float p3 = (1.0f - r0) * (1.0f - r2);
    int idx = 0;
    float best = p0;
    if (p1 > best) { best = p1; idx = 1; }
    if (p2 > best) { best = p2; idx = 2; }
    if (p3 > best) { best = p3; idx = 3; }
    sh_idx[tid] = (unsigned char)idx;
    __syncthreads();

    float* outb = out + (size_t)blockIdx.x * (256 * A);
    for (int i = tid; i < 256 * A; i += 256) {
        int bl = i / A;
        int a  = i - bl * A;
        outb[i] = sh_leaves[sh_idx[bl]][a];
    }
}

extern "C" void kernel_launch(void* const* d_in, const int* in_sizes, int n_in,
                              void* d_out, int out_size, void* d_ws, size_t ws_size,
                              hipStream_t stream) {
    const float* s  = (const float*)d_in[0];
    const float* W1 = (const float*)d_in[1];
    const float* b1 = (const float*)d_in[2];
    const float* W2 = (const float*)d_in[3];
    const float* b2 = (const float*)d_in[4];
    const float* W3 = (const float*)d_in[5];
    const float* b3 = (const float*)d_in[6];
    const float* ps = (const float*)d_in[7];
    const float* lv = (const float*)d_in[8];
    const float* gn = (const float*)d_in[9];
    float* ws  = (float*)d_ws;
    float* out = (float*)d_out;

    hipLaunchKernelGGL(ftc_setup, dim3(1), dim3(192), 0, stream,
                       W1, b1, W2, b2, W3, ws);
    hipLaunchKernelGGL(ftc_kernel, dim3(BTOT / 256), dim3(256), 0, stream,
                       s, W1, b1, W2, b2, W3, b3, ps, lv, gn, ws, out);
}